// Round 5
// baseline (136.465 us; speedup 1.0000x reference)
//
#include <hip/hip_runtime.h>
#include <stdint.h>

// covpool: y[b] = (1/256) X X^T - mu mu^T   (B=64, dim=512, M=256)
//
// Round-5: keep round-4's two-kernel barrier-free structure, fix the epilogue.
// Round-4's regression mechanism: 64 scalar 4B nontemporal stores/thread,
// scattered (4 rows x 64B = 256B per wave-store, partial lines) -> y's 64 MB
// crawled through a scatter write path. Fix: y is SYMMETRIC (covariance), so
// each lane's f32x4 (4 consecutive ROWS, one col in MFMA C-layout) is stored
// TRANSPOSED as y[col][row..row+3] -- same matrix by symmetry, and per store
// instr a wave now writes 16 rows x 64B contiguous = 16 FULL lines (1KB,
// dwordx4). Full-square 16 tiles/batch = bijection onto y. Zero LDS, zero
// barriers, no transpose buffer.
//
//   kernel 1 (prep): x f32 -> bf16 (RNE) into ws + row means. Streaming.
//   kernel 2 (gemm): 1024 blocks (64 batch x 16 tiles), 4 blocks/CU resident,
//                    fragments loaded per-lane from L2-resident bf16 panels
//                    (2 MB/XCD with batch-affine swizzle), acc -> direct
//                    transposed nontemporal f32x4 stores.

typedef __attribute__((ext_vector_type(8))) short bf16x8;   // 8 bf16 = 4 VGPRs
typedef __attribute__((ext_vector_type(4))) float f32x4;

static __device__ __forceinline__ unsigned short f2bf(float f) {
    union { float f; uint32_t u; } c; c.f = f;
    uint32_t u = c.u;
    return (unsigned short)((u + 0x7FFFu + ((u >> 16) & 1u)) >> 16);  // RNE
}

// ---------------- kernel 1: convert + row means ----------------
// 1024 blocks x 256 threads. Block = one 32-row segment of one batch.
// Batch->XCD mapping matches kernel 2 (blk&7 = xcd) so converted panels land
// in the L2 that will consume them.
__global__ __launch_bounds__(256) void covpool_prep(const float* __restrict__ x,
                                                    unsigned short* __restrict__ xbf,
                                                    float* __restrict__ mu) {
    const int blk = blockIdx.x;
    const int xcd = blk & 7, r = blk >> 3;       // r: 0..127
    const int b   = xcd * 8 + (r >> 4);          // 0..63
    const int seg = r & 15;                      // 32-row segment
    const size_t rowbase = (size_t)b * 512 + seg * 32;
    const float* xs = x + rowbase * 256;
    unsigned short* xd = xbf + rowbase * 256;
    const int tid = threadIdx.x;

#pragma unroll
    for (int it = 0; it < 4; ++it) {
        const int cid = it * 256 + tid;          // 8-float chunk id, 0..1023
        const int row = cid >> 5;                // 0..31 (32 chunks/row)
        const int sub = cid & 31;
        const float* g = xs + row * 256 + sub * 8;
        // nontemporal reads: x is read-once; keep L2 for the bf16 panels
        f32x4 v0 = __builtin_nontemporal_load((const f32x4*)g);
        f32x4 v1 = __builtin_nontemporal_load((const f32x4*)(g + 4));
        float s = (v0.x + v0.y + v0.z + v0.w) + (v1.x + v1.y + v1.z + v1.w);
        // row sum across the 32 lanes covering this row (xor<32 stays in group)
        s += __shfl_xor(s, 1, 64);  s += __shfl_xor(s, 2, 64);
        s += __shfl_xor(s, 4, 64);  s += __shfl_xor(s, 8, 64);
        s += __shfl_xor(s, 16, 64);
        bf16x8 o;
        o[0] = (short)f2bf(v0.x); o[1] = (short)f2bf(v0.y);
        o[2] = (short)f2bf(v0.z); o[3] = (short)f2bf(v0.w);
        o[4] = (short)f2bf(v1.x); o[5] = (short)f2bf(v1.y);
        o[6] = (short)f2bf(v1.z); o[7] = (short)f2bf(v1.w);
        *(bf16x8*)(xd + row * 256 + sub * 8) = o;   // plain store: want it in L2
        if (sub == 0) mu[rowbase + row] = s * (1.0f / 256.0f);
    }
}

// ---------------- kernel 2: barrier-free MFMA GEMM ----------------
// 1024 blocks x 256 threads: 64 batches x 16 (tm,tn) tiles of 128x128.
// 4 waves/block, each owns a 64x64 sub-tile (acc[4][4]).
__global__ __launch_bounds__(256, 4) void covpool_gemm(const unsigned short* __restrict__ xbf,
                                                       const float* __restrict__ mu,
                                                       float* __restrict__ y) {
    const int blk = blockIdx.x;
    const int xcd = blk & 7, r = blk >> 3;       // r: 0..127
    const int b   = xcd * 8 + (r >> 4);          // 0..63
    const int t   = r & 15;
    const int tm = t >> 2, tn = t & 3;

    const int tid  = threadIdx.x;
    const int lane = tid & 63;
    const int wave = tid >> 6;
    const int wm = (wave >> 1) * 64;
    const int wn = (wave & 1) * 64;
    const int rl = lane & 15;
    const int q  = lane >> 4;

    // Per-lane fragment bases: row (w*+idx*16+rl), k = kk*32 + q*8 (+0..7).
    const unsigned short* Ap = xbf + ((size_t)b * 512 + tm * 128 + wm + rl) * 256 + q * 8;
    const unsigned short* Bp = xbf + ((size_t)b * 512 + tn * 128 + wn + rl) * 256 + q * 8;

    f32x4 acc[4][4] = {};
#pragma unroll
    for (int kk = 0; kk < 8; ++kk) {
        bf16x8 bfr[4];
#pragma unroll
        for (int jj = 0; jj < 4; ++jj)
            bfr[jj] = *(const bf16x8*)(Bp + jj * (16 * 256) + kk * 32);
#pragma unroll
        for (int i = 0; i < 4; ++i) {            // af one-at-a-time: ~100 live VGPRs
            const bf16x8 af = *(const bf16x8*)(Ap + i * (16 * 256) + kk * 32);
#pragma unroll
            for (int jj = 0; jj < 4; ++jj)
                acc[i][jj] = __builtin_amdgcn_mfma_f32_16x16x32_bf16(
                    af, bfr[jj], acc[i][jj], 0, 0, 0);
        }
    }

    // Epilogue: y is symmetric -> store each lane's f32x4 transposed:
    //   val[rr] = y[R+rr][C] = y[C][R+rr],  R = tm*128+wm+i*16+q*4, C = tn*128+wn+jj*16+rl
    // Per store instr: 16 rows (rl) x 64B (q) = 16 full contiguous lines.
    const float* mub = mu + b * 512;
    f32x4 ma[4];
#pragma unroll
    for (int i = 0; i < 4; ++i)
        ma[i] = *(const f32x4*)(mub + tm * 128 + wm + i * 16 + q * 4);

    float* yb = y + (size_t)b * 512 * 512;
    const float inv256 = 1.0f / 256.0f;
#pragma unroll
    for (int jj = 0; jj < 4; ++jj) {
        const float mb = mub[tn * 128 + wn + jj * 16 + rl];
        float* yrow = yb + (size_t)(tn * 128 + wn + jj * 16 + rl) * 512 + tm * 128 + wm;
#pragma unroll
        for (int i = 0; i < 4; ++i) {
            f32x4 v;
#pragma unroll
            for (int rr = 0; rr < 4; ++rr)
                v[rr] = acc[i][jj][rr] * inv256 - ma[i][rr] * mb;
            __builtin_nontemporal_store(v, (f32x4*)(yrow + i * 16 + q * 4));
        }
    }
}

extern "C" void kernel_launch(void* const* d_in, const int* in_sizes, int n_in,
                              void* d_out, int out_size, void* d_ws, size_t ws_size,
                              hipStream_t stream) {
    const float* x = (const float*)d_in[0];
    float* yout = (float*)d_out;
    // workspace layout: [0,16MB) xbf (64*512*256 bf16), [16MB, +128KB) mu f32
    unsigned short* xbf = (unsigned short*)d_ws;
    float* mu = (float*)((char*)d_ws + (size_t)64 * 512 * 256 * 2);
    (void)ws_size; (void)in_sizes; (void)n_in; (void)out_size;
    covpool_prep<<<1024, 256, 0, stream>>>(x, xbf, mu);
    covpool_gemm<<<1024, 256, 0, stream>>>(xbf, mu, yout);
}

// Round 6
// 118.901 us; speedup vs baseline: 1.1477x; 1.1477x over previous
//
#include <hip/hip_runtime.h>
#include <stdint.h>

// covpool: y[b] = (1/256) X X^T - mu mu^T   (B=64, dim=512, M=256)
// Fused, upper-triangular tiles (10 blocks/batch); off-diag blocks emit both
// orientations via the chunked LDS transpose buffer.
//
// Round-6 = round-0 footprint x round-3 schedule (the two best variants):
//  * Double-buffered As/Bs (32 KB) -> ONE barrier per K-iter; staging of tile
//    k+1 runs after the MFMAs of tile k, prefetch of k+2 issued in the same
//    phase. (round-3 schedule)
//  * bar_lds = lgkmcnt(0)+s_barrier, NO vmcnt drain: prefetch loads stay in
//    flight across barriers, epilogue nt stores stream without drains. Safe:
//    no cross-wave hazard involves vmem (x read-only, y write-only). (round-3)
//  * Chunked 32x132 epilogue Ep UNIONED into the staging LDS (dead after the
//    K-loop) -> total LDS 33.8 KB -> 3 blocks/CU, all 640 blocks resident
//    (round-3's 68.6 KB union halved occupancy to 2/CU and masked the
//    schedule gains -- that was its regression mechanism). (round-0 footprint)
//  * 1/16 pre-scale folded into epilogue as 1/256 (exponent-only in bf16,
//    bitwise-same mantissas); nontemporal y stores (write-once).

typedef __attribute__((ext_vector_type(8))) short bf16x8;   // 8 bf16 = 4 VGPRs
typedef __attribute__((ext_vector_type(4))) float f32x4;

static __device__ __forceinline__ unsigned short f2bf(float f) {
    union { float f; uint32_t u; } c; c.f = f;
    uint32_t u = c.u;
    return (unsigned short)((u + 0x7FFFu + ((u >> 16) & 1u)) >> 16);  // RNE
}

static __device__ __forceinline__ void cvt_store(f32x4 v0, f32x4 v1, float* psum,
                                                 unsigned short* dst) {
    *psum += (v0.x + v0.y + v0.z + v0.w) + (v1.x + v1.y + v1.z + v1.w);
    bf16x8 o;
    o[0] = (short)f2bf(v0.x); o[1] = (short)f2bf(v0.y);
    o[2] = (short)f2bf(v0.z); o[3] = (short)f2bf(v0.w);
    o[4] = (short)f2bf(v1.x); o[5] = (short)f2bf(v1.y);
    o[6] = (short)f2bf(v1.z); o[7] = (short)f2bf(v1.w);
    *(bf16x8*)dst = o;
}

// LDS barrier: drain own LDS ops, cross the barrier, fence the compiler.
// Deliberately NO vmcnt drain (verified correct in round 3).
static __device__ __forceinline__ void bar_lds() {
    asm volatile("s_waitcnt lgkmcnt(0)" ::: "memory");
    __builtin_amdgcn_s_barrier();
    asm volatile("" ::: "memory");
}

__global__ __launch_bounds__(256) void covpool_fused(const float* __restrict__ x,
                                                     float* __restrict__ y) {
    // Staging: buf p -> A at shorts [p*8192, +4096), B at [p*8192+4096, +4096).
    // Epilogue Ep[32][132] f32 (16896 B) aliases the front of this region
    // (staging dead after the K-loop; bar_lds separates last reads from writes).
    __shared__ __align__(16) unsigned short SU[16384];   // 32 KB
    __shared__ float muA[128];
    __shared__ float muB[128];
    float* const Ep = (float*)SU;

    // 640 blocks: XCD swizzle (blockIdx%8 -> XCD), 8 batches/XCD x 10 upper-tri tiles
    const int xcd = blockIdx.x & 7;
    const int j   = blockIdx.x >> 3;         // 0..79
    const int b   = xcd * 8 + j / 10;        // 0..63
    const int t10 = j % 10;
    // nibble LUT: t10 -> (tm<<2|tn) over {(0,0)..(3,3), tm<=tn}
    const unsigned code = (unsigned)((0xFBA7653210ULL >> (4 * t10)) & 15ULL);
    const int tm = code >> 2, tn = code & 3;
    const bool diag = (tm == tn);

    const float* Ag = x + ((size_t)b * 512 + tm * 128) * 256;
    const float* Bg = x + ((size_t)b * 512 + tn * 128) * 256;

    const int tid  = threadIdx.x;
    const int lane = tid & 63;
    const int wave = tid >> 6;
    const int wm = (wave >> 1) * 64;
    const int wn = (wave & 1) * 64;

    f32x4 acc[4][4] = {};
    float pA[2] = {0.f, 0.f}, pB[2] = {0.f, 0.f};

    const int rl  = lane & 15;
    const int q   = lane >> 4;
    const int swl = (q ^ ((rl >> 1) & 3)) * 8;   // swizzled read slot (shorts)
    const int srow = tid >> 2, schunk = tid & 3; // srow 0..63 (+64 via t)
    const int slot = schunk ^ ((srow >> 1) & 3); // t-independent

    // ---- prologue: load+stage tile 0 into buf0, issue loads for tile 1 ----
    f32x4 a0[2], a1[2], b0[2], b1[2];
#pragma unroll
    for (int t = 0; t < 2; ++t) {
        const float* g = Ag + (size_t)(t * 64 + srow) * 256 + schunk * 8;
        a0[t] = *(const f32x4*)g; a1[t] = *(const f32x4*)(g + 4);
        if (!diag) {
            const float* h = Bg + (size_t)(t * 64 + srow) * 256 + schunk * 8;
            b0[t] = *(const f32x4*)h; b1[t] = *(const f32x4*)(h + 4);
        }
    }
#pragma unroll
    for (int t = 0; t < 2; ++t) {
        const int row = t * 64 + srow;
        cvt_store(a0[t], a1[t], &pA[t], SU + row * 32 + slot * 8);
        if (!diag) cvt_store(b0[t], b1[t], &pB[t], SU + 4096 + row * 32 + slot * 8);
    }
#pragma unroll
    for (int t = 0; t < 2; ++t) {
        const float* g = Ag + (size_t)(t * 64 + srow) * 256 + 32 + schunk * 8;
        a0[t] = *(const f32x4*)g; a1[t] = *(const f32x4*)(g + 4);
        if (!diag) {
            const float* h = Bg + (size_t)(t * 64 + srow) * 256 + 32 + schunk * 8;
            b0[t] = *(const f32x4*)h; b1[t] = *(const f32x4*)(h + 4);
        }
    }
    bar_lds();   // buf0 visible; tile-1 loads remain in flight

    // ---- K-loop: 8 iters, 1 barrier each. Read buf[kk&1]; stage kk+1 into buf^1. ----
#pragma unroll
    for (int kk = 0; kk < 8; ++kk) {
        const unsigned short* Acur = SU + (kk & 1) * 8192;
        const unsigned short* Bcur = diag ? Acur : (Acur + 4096);
        bf16x8 af[4], bfr[4];
#pragma unroll
        for (int i = 0; i < 4; ++i)
            af[i] = *(const bf16x8*)(Acur + (wm + i * 16 + rl) * 32 + swl);
#pragma unroll
        for (int jj = 0; jj < 4; ++jj)
            bfr[jj] = *(const bf16x8*)(Bcur + (wn + jj * 16 + rl) * 32 + swl);
#pragma unroll
        for (int i = 0; i < 4; ++i)
#pragma unroll
            for (int jj = 0; jj < 4; ++jj)
                acc[i][jj] = __builtin_amdgcn_mfma_f32_16x16x32_bf16(
                    af[i], bfr[jj], acc[i][jj], 0, 0, 0);
        if (kk < 7) {
            const int nb = ((kk + 1) & 1) * 8192;
#pragma unroll
            for (int t = 0; t < 2; ++t) {       // stage tile kk+1 (regs already loaded)
                const int row = t * 64 + srow;
                cvt_store(a0[t], a1[t], &pA[t], SU + nb + row * 32 + slot * 8);
                if (!diag) cvt_store(b0[t], b1[t], &pB[t],
                                     SU + nb + 4096 + row * 32 + slot * 8);
            }
            if (kk < 6) {                       // issue loads for tile kk+2
#pragma unroll
                for (int t = 0; t < 2; ++t) {
                    const float* g = Ag + (size_t)(t * 64 + srow) * 256 + (kk + 2) * 32 + schunk * 8;
                    a0[t] = *(const f32x4*)g; a1[t] = *(const f32x4*)(g + 4);
                    if (!diag) {
                        const float* h = Bg + (size_t)(t * 64 + srow) * 256 + (kk + 2) * 32 + schunk * 8;
                        b0[t] = *(const f32x4*)h; b1[t] = *(const f32x4*)(h + 4);
                    }
                }
            }
            bar_lds();   // buf^1 writes visible; buf reads done (WAR safe)
        }
    }

    // ---- row means: staged vals are raw x, mu = rowsum/256 ----
#pragma unroll
    for (int t = 0; t < 2; ++t) {
        float s = pA[t];
        s += __shfl_xor(s, 1, 64); s += __shfl_xor(s, 2, 64);
        if (schunk == 0) muA[t * 64 + srow] = s * (1.0f / 256.0f);
        if (!diag) {
            float sb = pB[t];
            sb += __shfl_xor(sb, 1, 64); sb += __shfl_xor(sb, 2, 64);
            if (schunk == 0) muB[t * 64 + srow] = sb * (1.0f / 256.0f);
        }
    }
    const float* muBp = diag ? muA : muB;
    float* yb = y + (size_t)b * 512 * 512;
    const float inv256 = 1.0f / 256.0f;

    // ---- epilogue: 4 chunks of 32 rows through Ep[32][132] (aliases staging) ----
#pragma unroll
    for (int c = 0; c < 4; ++c) {
        bar_lds();   // first iter: mu visible + last frag reads drained; later: Ep reads done
        if ((wave >> 1) == (c >> 1)) {       // rows 32c..32c+31 live in this wave's acc
            const int ii0 = 2 * (c & 1);
#pragma unroll
            for (int ii = 0; ii < 2; ++ii) {
                const int i = ii0 + ii;
#pragma unroll
                for (int jj = 0; jj < 4; ++jj) {
                    const int col = wn + jj * 16 + rl;
                    const float mb = muBp[col];
#pragma unroll
                    for (int r = 0; r < 4; ++r) {
                        const int row = wm + i * 16 + q * 4 + r;
                        Ep[(ii * 16 + q * 4 + r) * 132 + col] =
                            acc[i][jj][r] * inv256 - muA[row] * mb;
                    }
                }
            }
        }
        bar_lds();
        // normal orientation: 512B-contiguous dwordx4 runs, nontemporal
#pragma unroll
        for (int v = 0; v < 4; ++v) {
            const int flat = v * 256 + tid;          // 0..1023
            const int rloc = flat >> 5, c4 = flat & 31;
            f32x4 val = *(const f32x4*)(Ep + rloc * 132 + c4 * 4);
            __builtin_nontemporal_store(
                val, (f32x4*)(yb + (size_t)(tm * 128 + c * 32 + rloc) * 512 + tn * 128 + c4 * 4));
        }
        if (!diag) {  // mirror: y[col][row] = same value, read Ep transposed
#pragma unroll
            for (int v = 0; v < 4; ++v) {
                const int id = v * 256 + tid;        // 0..1023
                const int cc = id >> 3, g = id & 7;  // cc: tile col, g: 4-row group
                f32x4 val;
#pragma unroll
                for (int e = 0; e < 4; ++e)
                    val[e] = Ep[(g * 4 + e) * 132 + cc];
                __builtin_nontemporal_store(
                    val, (f32x4*)(yb + (size_t)(tn * 128 + cc) * 512 + tm * 128 + c * 32 + g * 4));
            }
        }
    }
}

extern "C" void kernel_launch(void* const* d_in, const int* in_sizes, int n_in,
                              void* d_out, int out_size, void* d_ws, size_t ws_size,
                              hipStream_t stream) {
    const float* x = (const float*)d_in[0];
    float* yout = (float*)d_out;
    (void)d_ws; (void)ws_size; (void)in_sizes; (void)n_in; (void)out_size;
    covpool_fused<<<640, 256, 0, stream>>>(x, yout);
}

// Round 7
// 113.757 us; speedup vs baseline: 1.1996x; 1.0452x over previous
//
#include <hip/hip_runtime.h>
#include <stdint.h>

// covpool: y[b] = (1/256) X X^T - mu mu^T   (B=64, dim=512, M=256)
//
// Round-7: two kernels, gemm staged via global_load_lds (the combination not
// yet tried). Six fused rounds proved the fused K-loop's per-iter chain
// (vmcnt -> ~200 VALU cvt -> ds_write -> lgkm -> barrier -> ds_read -> MFMA)
// is the floor (36-46us, all pipes <12%, zero spill, zero overfetch): with the
// whole grid resident in one generation, makespan = that chain x 8 iters.
// Rounds 4/5 proved direct per-lane L2 fragment gathers are worse (no reuse).
// Fix: convert ONCE (prep), then GEMM stages bf16 panels by pure DMA
// (global_load_lds dwordx4): no conversion VALU, no VGPR round-trip, barrier
// drains via __syncthreads (m97-verified structure, 874 TF on real GEMMs).
//
//  prep: x f32 -> bf16 RNE (identical numerics to all passing rounds) + row
//        means. Streaming, ~48 MB traffic.
//  gemm: 1024 blocks = 64 batches x 16 tiles of 128x128, 4 waves/block.
//        LDS 32KB: A/B double-buffered [128 rows][32 bf16] per K-step.
//        Layout note: frag read af[i] covers a contiguous 1KB span per wave
//        (row=rl, chunk=q), one distinct aligned 16B per lane -> bank-
//        conflict-free with NO swizzle, and identical to the linear lane-
//        ordered dest global_load_lds requires (LDS byte tid*16 == row
//        (tid>>2), chunk (tid&3)).
//        Epilogue: y symmetric -> store each lane's f32x4 transposed
//        y[C][R..R+3] (verified round 5): 16 full 64B lines per store instr,
//        zero LDS, zero barriers. PLAIN stores (every nt variant measured
//        slower; round-0 best used plain).

typedef __attribute__((ext_vector_type(8))) short bf16x8;   // 8 bf16 = 4 VGPRs
typedef __attribute__((ext_vector_type(4))) float f32x4;

static __device__ __forceinline__ unsigned short f2bf(float f) {
    union { float f; uint32_t u; } c; c.f = f;
    uint32_t u = c.u;
    return (unsigned short)((u + 0x7FFFu + ((u >> 16) & 1u)) >> 16);  // RNE
}

static __device__ __forceinline__ void gload16(const unsigned short* g, unsigned short* l) {
    __builtin_amdgcn_global_load_lds(
        (const __attribute__((address_space(1))) void*)g,
        (__attribute__((address_space(3))) void*)l, 16, 0, 0);
}

// ---------------- kernel 1: convert + row means ----------------
// 1024 blocks x 256 threads; block = one 32-row segment of one batch.
// Same batch->XCD affinity as gemm (blk&7) so panels land in the consuming L2.
__global__ __launch_bounds__(256) void covpool_prep(const float* __restrict__ x,
                                                    unsigned short* __restrict__ xbf,
                                                    float* __restrict__ mu) {
    const int blk = blockIdx.x;
    const int xcd = blk & 7, r = blk >> 3;       // r: 0..127
    const int b   = xcd * 8 + (r >> 4);          // 0..63
    const int seg = r & 15;                      // 32-row segment
    const size_t rowbase = (size_t)b * 512 + seg * 32;
    const float* xs = x + rowbase * 256;
    unsigned short* xd = xbf + rowbase * 256;
    const int tid = threadIdx.x;

#pragma unroll
    for (int it = 0; it < 4; ++it) {
        const int cid = it * 256 + tid;          // 8-float chunk id, 0..1023
        const int row = cid >> 5;                // 0..31 (32 chunks/row)
        const int sub = cid & 31;
        const float* g = xs + row * 256 + sub * 8;
        // nt reads: x is read-once; keep L2/L3 for the bf16 panels + y
        f32x4 v0 = __builtin_nontemporal_load((const f32x4*)g);
        f32x4 v1 = __builtin_nontemporal_load((const f32x4*)(g + 4));
        float s = (v0.x + v0.y + v0.z + v0.w) + (v1.x + v1.y + v1.z + v1.w);
        s += __shfl_xor(s, 1, 64);  s += __shfl_xor(s, 2, 64);
        s += __shfl_xor(s, 4, 64);  s += __shfl_xor(s, 8, 64);
        s += __shfl_xor(s, 16, 64);              // row sum over the row's 32 lanes
        bf16x8 o;
        o[0] = (short)f2bf(v0.x); o[1] = (short)f2bf(v0.y);
        o[2] = (short)f2bf(v0.z); o[3] = (short)f2bf(v0.w);
        o[4] = (short)f2bf(v1.x); o[5] = (short)f2bf(v1.y);
        o[6] = (short)f2bf(v1.z); o[7] = (short)f2bf(v1.w);
        *(bf16x8*)(xd + row * 256 + sub * 8) = o;   // plain store: want it cached
        if (sub == 0) mu[rowbase + row] = s * (1.0f / 256.0f);
    }
}

// ---------------- kernel 2: DMA-staged MFMA GEMM ----------------
__global__ __launch_bounds__(256) void covpool_gemm(const unsigned short* __restrict__ xbf,
                                                    const float* __restrict__ mu,
                                                    float* __restrict__ y) {
    // [buf][row 0..127][32 bf16] = 8KB per matrix per buf -> 32 KB total
    __shared__ __align__(16) unsigned short As[2][4096];
    __shared__ __align__(16) unsigned short Bs[2][4096];

    const int blk = blockIdx.x;
    const int xcd = blk & 7, r = blk >> 3;       // r: 0..127
    const int b   = xcd * 8 + (r >> 4);          // 0..63
    const int t   = r & 15;
    const int tm = t >> 2, tn = t & 3;
    const bool diag = (tm == tn);

    const int tid  = threadIdx.x;
    const int lane = tid & 63;
    const int wave = tid >> 6;
    const int wm = (wave >> 1) * 64;
    const int wn = (wave & 1) * 64;
    const int rl = lane & 15;
    const int q  = lane >> 4;

    // staging: thread tid supplies LDS bytes [tq*4096 + tid*16): row tq*64+(tid>>2),
    // k-chunk (tid&3) -> global row-major source address (lane-ordered, linear dest).
    const int srow = tid >> 2, sch = tid & 3;
    const unsigned short* Ag = xbf + ((size_t)b * 512 + tm * 128 + srow) * 256 + sch * 8;
    const unsigned short* Bg = xbf + ((size_t)b * 512 + tn * 128 + srow) * 256 + sch * 8;
    const int ldst = tid * 8;                    // short offset within 2048-short half

    // prologue: stage tile 0 into buf 0
#pragma unroll
    for (int tq = 0; tq < 2; ++tq) {
        gload16(Ag + tq * (64 * 256), &As[0][tq * 2048 + ldst]);
        if (!diag) gload16(Bg + tq * (64 * 256), &Bs[0][tq * 2048 + ldst]);
    }

    f32x4 acc[4][4] = {};
#pragma unroll
    for (int kk = 0; kk < 8; ++kk) {
        __syncthreads();                         // vmcnt(0)+lgkm(0): buf[kk&1] ready, other buf's reads done
        if (kk < 7) {                            // DMA tile kk+1 into the other buffer
            const int nb = (kk + 1) & 1;
            const int ko = (kk + 1) * 32;
#pragma unroll
            for (int tq = 0; tq < 2; ++tq) {
                gload16(Ag + tq * (64 * 256) + ko, &As[nb][tq * 2048 + ldst]);
                if (!diag) gload16(Bg + tq * (64 * 256) + ko, &Bs[nb][tq * 2048 + ldst]);
            }
        }
        const unsigned short* Acur = As[kk & 1];
        const unsigned short* Bcur = diag ? Acur : Bs[kk & 1];
        bf16x8 af[4], bfr[4];
#pragma unroll
        for (int i = 0; i < 4; ++i)
            af[i] = *(const bf16x8*)(Acur + (wm + i * 16 + rl) * 32 + q * 8);
#pragma unroll
        for (int jj = 0; jj < 4; ++jj)
            bfr[jj] = *(const bf16x8*)(Bcur + (wn + jj * 16 + rl) * 32 + q * 8);
#pragma unroll
        for (int i = 0; i < 4; ++i)
#pragma unroll
            for (int jj = 0; jj < 4; ++jj)
                acc[i][jj] = __builtin_amdgcn_mfma_f32_16x16x32_bf16(
                    af[i], bfr[jj], acc[i][jj], 0, 0, 0);
    }

    // Epilogue: y[R][C] = y[C][R] (symmetric) -> store lane's f32x4 transposed:
    // y[C][R..R+3], R = tm*128+wm+i*16+q*4, C = tn*128+wn+jj*16+rl.
    // Per store instr: 16 rows (rl) x 64B (q,i) contiguous = full lines.
    const float* mub = mu + b * 512;
    f32x4 ma[4];
#pragma unroll
    for (int i = 0; i < 4; ++i)
        ma[i] = *(const f32x4*)(mub + tm * 128 + wm + i * 16 + q * 4);

    float* yb = y + (size_t)b * 512 * 512;
    const float inv256 = 1.0f / 256.0f;
#pragma unroll
    for (int jj = 0; jj < 4; ++jj) {
        const float mb = mub[tn * 128 + wn + jj * 16 + rl];
        float* yrow = yb + (size_t)(tn * 128 + wn + jj * 16 + rl) * 512 + tm * 128 + wm;
#pragma unroll
        for (int i = 0; i < 4; ++i) {
            f32x4 v;
#pragma unroll
            for (int rr = 0; rr < 4; ++rr)
                v[rr] = acc[i][jj][rr] * inv256 - ma[i][rr] * mb;
            *(f32x4*)(yrow + i * 16 + q * 4) = v;    // plain store (nt measured slower)
        }
    }
}

extern "C" void kernel_launch(void* const* d_in, const int* in_sizes, int n_in,
                              void* d_out, int out_size, void* d_ws, size_t ws_size,
                              hipStream_t stream) {
    const float* x = (const float*)d_in[0];
    float* yout = (float*)d_out;
    // workspace: [0,16MB) xbf (64*512*256 bf16), [16MB,+128KB) mu f32
    unsigned short* xbf = (unsigned short*)d_ws;
    float* mu = (float*)((char*)d_ws + (size_t)64 * 512 * 256 * 2);
    (void)ws_size; (void)in_sizes; (void)n_in; (void)out_size;
    covpool_prep<<<1024, 256, 0, stream>>>(x, xbf, mu);
    covpool_gemm<<<1024, 256, 0, stream>>>(xbf, mu, yout);
}

// Round 8
// 104.033 us; speedup vs baseline: 1.3118x; 1.0935x over previous
//
#include <hip/hip_runtime.h>
#include <stdint.h>

// covpool: y[b] = (1/M) Xc Xc^T = (1/16 X)(1/16 X)^T - mu mu^T   (M=256)
// One fused kernel (round-0 artifact, 104us): upper-triangular tiles only
// (10/batch), K-loop register-prefetches the next chunk.
//
// Round-8 change (ONLY the epilogue; staging/K-loop byte-identical to round 0):
//  * Off-diag MIRROR tile stored DIRECTLY from acc (round-5-verified pattern):
//    by symmetry y[R][C]=y[C][R], and the MFMA C-layout gives each lane 4
//    consecutive tile-rows x 1 col -> y[C][R..R+3] is a contiguous f32x4;
//    per store instr a wave writes 16 full 64B lines. This deletes the 16
//    transposed Ep gather-reads/thread and the mirror's share of the chunked
//    barrier loop, and starts the y write stream earlier (tail shortening —
//    the timed region is write-traffic dominated: 512MB fills + 64MB y).
//  * Normal orientation unchanged: Ep[32][132] chunks, plain coalesced stores.
// No workspace, no nt stores, no extra write bytes (write-model lesson of r1-r7).

typedef __attribute__((ext_vector_type(8))) short bf16x8;   // 8 bf16 = 4 VGPRs
typedef __attribute__((ext_vector_type(4))) float f32x4;

static __device__ __forceinline__ unsigned short f2bf(float f) {
    union { float f; uint32_t u; } c; c.f = f;
    uint32_t u = c.u;
    return (unsigned short)((u + 0x7FFFu + ((u >> 16) & 1u)) >> 16);  // RNE
}

static __device__ __forceinline__ void cvt_store(f32x4 v0, f32x4 v1, float* psum,
                                                 unsigned short* dst) {
    v0 *= 0.0625f; v1 *= 0.0625f;
    *psum += (v0.x + v0.y + v0.z + v0.w) + (v1.x + v1.y + v1.z + v1.w);
    bf16x8 o;
    o[0] = (short)f2bf(v0.x); o[1] = (short)f2bf(v0.y);
    o[2] = (short)f2bf(v0.z); o[3] = (short)f2bf(v0.w);
    o[4] = (short)f2bf(v1.x); o[5] = (short)f2bf(v1.y);
    o[6] = (short)f2bf(v1.z); o[7] = (short)f2bf(v1.w);
    *(bf16x8*)dst = o;
}

__global__ __launch_bounds__(256) void covpool_fused(const float* __restrict__ x,
                                                     float* __restrict__ y) {
    __shared__ __align__(16) unsigned short As[128 * 32];  // [row][slot], slot=chunk^((row>>1)&3)
    __shared__ __align__(16) unsigned short Bs[128 * 32];
    __shared__ __align__(16) float Ep[32 * 132];           // epilogue transpose buffer
    __shared__ __align__(16) float muA[128];
    __shared__ __align__(16) float muB[128];

    // 640 blocks: XCD swizzle (blockIdx%8 -> XCD), 8 batches/XCD x 10 upper-tri tiles
    const int xcd = blockIdx.x & 7;
    const int j   = blockIdx.x >> 3;         // 0..79
    const int b   = xcd * 8 + j / 10;        // 0..63
    const int t10 = j % 10;
    // nibble LUT: t10 -> (tm<<2|tn) over {(0,0)..(3,3), tm<=tn}
    const unsigned code = (unsigned)((0xFBA7653210ULL >> (4 * t10)) & 15ULL);
    const int tm = code >> 2, tn = code & 3;
    const bool diag = (tm == tn);

    const float* Ag = x + ((size_t)b * 512 + tm * 128) * 256;
    const float* Bg = x + ((size_t)b * 512 + tn * 128) * 256;

    const int tid  = threadIdx.x;
    const int lane = tid & 63;
    const int wave = tid >> 6;
    const int wm = (wave >> 1) * 64;
    const int wn = (wave & 1) * 64;

    f32x4 acc[4][4] = {};
    float pA[2] = {0.f, 0.f}, pB[2] = {0.f, 0.f};

    const int rl  = lane & 15;
    const int q   = lane >> 4;
    const int swl = (q ^ ((rl >> 1) & 3)) * 8;   // swizzled read slot (shorts)
    const int srow = tid >> 2, schunk = tid & 3;

    // prefetch kk=0 into registers
    f32x4 a0[2], a1[2], b0[2], b1[2];
#pragma unroll
    for (int t = 0; t < 2; ++t) {
        const float* g = Ag + (size_t)(t * 64 + srow) * 256 + schunk * 8;
        a0[t] = *(const f32x4*)g; a1[t] = *(const f32x4*)(g + 4);
        if (!diag) {
            const float* h = Bg + (size_t)(t * 64 + srow) * 256 + schunk * 8;
            b0[t] = *(const f32x4*)h; b1[t] = *(const f32x4*)(h + 4);
        }
    }

    for (int kk = 0; kk < 256; kk += 32) {
        __syncthreads();                     // prev iter's fragment reads done
#pragma unroll
        for (int t = 0; t < 2; ++t) {
            const int row  = t * 64 + srow;
            const int slot = schunk ^ ((row >> 1) & 3);
            cvt_store(a0[t], a1[t], &pA[t], As + row * 32 + slot * 8);
            if (!diag) cvt_store(b0[t], b1[t], &pB[t], Bs + row * 32 + slot * 8);
        }
        __syncthreads();
        if (kk < 224) {                      // issue next chunk; waited at next cvt_store
#pragma unroll
            for (int t = 0; t < 2; ++t) {
                const float* g = Ag + (size_t)(t * 64 + srow) * 256 + (kk + 32) + schunk * 8;
                a0[t] = *(const f32x4*)g; a1[t] = *(const f32x4*)(g + 4);
                if (!diag) {
                    const float* h = Bg + (size_t)(t * 64 + srow) * 256 + (kk + 32) + schunk * 8;
                    b0[t] = *(const f32x4*)h; b1[t] = *(const f32x4*)(h + 4);
                }
            }
        }
        const unsigned short* Bsrc = diag ? As : Bs;
        bf16x8 af[4], bfr[4];
#pragma unroll
        for (int i = 0; i < 4; ++i)
            af[i] = *(const bf16x8*)(As + (wm + i * 16 + rl) * 32 + swl);
#pragma unroll
        for (int jj = 0; jj < 4; ++jj)
            bfr[jj] = *(const bf16x8*)(Bsrc + (wn + jj * 16 + rl) * 32 + swl);
#pragma unroll
        for (int i = 0; i < 4; ++i)
#pragma unroll
            for (int jj = 0; jj < 4; ++jj)
                acc[i][jj] = __builtin_amdgcn_mfma_f32_16x16x32_bf16(
                    af[i], bfr[jj], acc[i][jj], 0, 0, 0);
    }

    // row means: 4 staging threads per row; staged vals are x/16 so mu = rowsum/16
#pragma unroll
    for (int t = 0; t < 2; ++t) {
        float s = pA[t];
        s += __shfl_xor(s, 1, 64); s += __shfl_xor(s, 2, 64);
        if (schunk == 0) muA[t * 64 + srow] = s * 0.0625f;
        if (!diag) {
            float sb = pB[t];
            sb += __shfl_xor(sb, 1, 64); sb += __shfl_xor(sb, 2, 64);
            if (schunk == 0) muB[t * 64 + srow] = sb * 0.0625f;
        }
    }
    const float* muBp = diag ? muA : muB;
    float* yb = y + (size_t)b * 512 * 512;

    __syncthreads();                         // mu visible to all waves

    // ---- off-diag mirror tile DIRECT from acc (no LDS, no barriers) ----
    // y[tn*128 + C][tm*128 + R..R+3] = acc - muA[R..]*muB[C]; C = wn+jj*16+rl,
    // R = wm+i*16+q*4. Per store instr: 16 rows x 64B contiguous = full lines.
    if (!diag) {
        f32x4 ma[4];
#pragma unroll
        for (int i = 0; i < 4; ++i)
            ma[i] = *(const f32x4*)(muA + wm + i * 16 + q * 4);
#pragma unroll
        for (int jj = 0; jj < 4; ++jj) {
            const float mb = muB[wn + jj * 16 + rl];
            float* yrow = yb + (size_t)(tn * 128 + wn + jj * 16 + rl) * 512 + tm * 128 + wm;
#pragma unroll
            for (int i = 0; i < 4; ++i) {
                f32x4 v;
#pragma unroll
                for (int rr = 0; rr < 4; ++rr)
                    v[rr] = acc[i][jj][rr] - ma[i][rr] * mb;
                *(f32x4*)(yrow + i * 16 + q * 4) = v;
            }
        }
    }

    // ---- normal orientation via Ep chunks (round-0 path; mirror removed) ----
#pragma unroll
    for (int c = 0; c < 4; ++c) {
        __syncthreads();                     // Ep free (prev chunk's reads done)
        if ((wave >> 1) == (c >> 1)) {       // rows 32c..32c+31 live in this wave's acc
            const int ii0 = 2 * (c & 1);
#pragma unroll
            for (int ii = 0; ii < 2; ++ii) {
                const int i = ii0 + ii;
#pragma unroll
                for (int jj = 0; jj < 4; ++jj) {
                    const int col = wn + jj * 16 + rl;
                    const float mb = muBp[col];
#pragma unroll
                    for (int r = 0; r < 4; ++r) {
                        const int row = wm + i * 16 + q * 4 + r;
                        Ep[(ii * 16 + q * 4 + r) * 132 + col] = acc[i][jj][r] - muA[row] * mb;
                    }
                }
            }
        }
        __syncthreads();
        // 512B-contiguous dwordx4 runs
#pragma unroll
        for (int v = 0; v < 4; ++v) {
            const int flat = v * 256 + tid;          // 0..1023
            const int rloc = flat >> 5, c4 = flat & 31;
            f32x4 val = *(const f32x4*)(Ep + rloc * 132 + c4 * 4);
            *(f32x4*)(yb + (size_t)(tm * 128 + c * 32 + rloc) * 512 + tn * 128 + c4 * 4) = val;
        }
    }
}

extern "C" void kernel_launch(void* const* d_in, const int* in_sizes, int n_in,
                              void* d_out, int out_size, void* d_ws, size_t ws_size,
                              hipStream_t stream) {
    const float* x = (const float*)d_in[0];
    float* yout = (float*)d_out;
    (void)d_ws; (void)ws_size; (void)in_sizes; (void)n_in; (void)out_size;
    covpool_fused<<<640, 256, 0, stream>>>(x, yout);
}